// Round 6
// baseline (475.688 us; speedup 1.0000x reference)
//
#include <hip/hip_runtime.h>
#include <hip/hip_bf16.h>
#include <stdint.h>

typedef __bf16 bf16_t;
typedef bf16_t bf16x8 __attribute__((ext_vector_type(8)));
typedef bf16_t bf16x4 __attribute__((ext_vector_type(4)));
typedef float f32x4 __attribute__((ext_vector_type(4)));

#define NN 10000
#define EE 80000
#define DD 1024
#define LL 2
#define MPAD 10112   /* 79*128 */
#define NEGS 0.2f

#define GLOAD_LDS16(g, l) \
    __builtin_amdgcn_global_load_lds((__attribute__((address_space(1))) void*)(void*)(g), \
                                     (__attribute__((address_space(3))) void*)(l), 16, 0, 0)

// ---------------------------------------------------------------- mega-preamble
// blocks [0,5120): transpose 5x 1024^2 fp32->bf16 (Wl0,Wr0,Wl1,Wr1,outW)
// blocks [5120,10176): h_init ; [10176,10196): bias pack ;
// blocks [10196,10220): zero M3L ; [10220,10260): zero deg
__global__ __launch_bounds__(256)
void preamble(const float* __restrict__ Wl, const float* __restrict__ Wr,
              const float* __restrict__ outW, bf16_t* __restrict__ WT,
              bf16_t* __restrict__ OWT,
              const float* __restrict__ x, const int* __restrict__ ntypes,
              const float* __restrict__ nte, bf16_t* __restrict__ hbuf,
              const float* __restrict__ bl, const float* __restrict__ br,
              const float* __restrict__ outb, float* __restrict__ biasb,
              float* __restrict__ M3L, int* __restrict__ deg)
{
    __shared__ float tile[32][33];
    int b = blockIdx.x;
    int tid = threadIdx.x;
    if (b < 5120) {
        int z = b >> 10, rem = b & 1023;
        int bx = rem & 31, by = rem >> 5;
        const float* src;
        bf16_t* dstp;
        switch (z) {
            case 0: src = Wl;                       dstp = WT;                        break;
            case 1: src = Wr;                       dstp = WT + (size_t)1024*1024;    break;
            case 2: src = Wl + (size_t)1024*1024;   dstp = WT + (size_t)2*1024*1024;  break;
            case 3: src = Wr + (size_t)1024*1024;   dstp = WT + (size_t)3*1024*1024;  break;
            default: src = outW;                    dstp = OWT;                       break;
        }
        int tx = tid & 31, ty = tid >> 5;
#pragma unroll
        for (int i = 0; i < 4; ++i)
            tile[ty + i*8][tx] = src[(size_t)(by*32 + ty + i*8)*1024 + bx*32 + tx];
        __syncthreads();
#pragma unroll
        for (int i = 0; i < 4; ++i)
            dstp[(size_t)(bx*32 + ty + i*8)*1024 + by*32 + tx] = (bf16_t)tile[tx][ty + i*8];
    } else if (b < 10176) {
        size_t idx = ((size_t)(b - 5120)*256 + tid) * 8;
        if (idx >= (size_t)MPAD*1024) return;
        int n = (int)(idx >> 10);
        int c = (int)(idx & 1023);
        bf16x8 outv;
        if (n < NN) {
            const float* xp = x + (size_t)n*1024 + c;
            int t = ntypes[n];
            const float* ep = nte + (size_t)t*1024 + c;
#pragma unroll
            for (int j = 0; j < 8; ++j) outv[j] = (bf16_t)(xp[j] + ep[j]);
        } else {
#pragma unroll
            for (int j = 0; j < 8; ++j) outv[j] = (bf16_t)0.f;
        }
        *(bf16x8*)(hbuf + idx) = outv;
    } else if (b < 10196) {
        int i = (b - 10176)*256 + tid;
        if (i < 4096) {
            int l = i >> 11, j = i & 2047;
            biasb[i] = (j < 1024) ? bl[l*1024 + j] : br[l*1024 + j - 1024];
        } else if (i < 5120) {
            biasb[i] = outb[i - 4096];
        }
    } else if (b < 10220) {
        int i = (b - 10196)*256 + tid;
        if (i < LL*3072) M3L[i] = 0.f;
    } else {
        int i = (b - 10220)*256 + tid;
        if (i < NN) deg[i] = 0;
    }
}

// ---------------------------------------------------------------- M3 (both layers, one launch)
__global__ __launch_bounds__(256)
void compute_m3_all(const float* __restrict__ ete, const float* __restrict__ We,
                    float* __restrict__ M3L)
{
    int l   = blockIdx.x >> 8;
    int bid = blockIdx.x & 255;
    const float* WeL = We + (size_t)l*1024*1024;
    float* M3 = M3L + l*3072;
    int j  = (bid & 3) * 256 + threadIdx.x;
    int k0 = (bid >> 2) * 16;
    float a0 = 0.f, a1 = 0.f, a2 = 0.f;
#pragma unroll
    for (int kk = 0; kk < 16; ++kk) {
        int k = k0 + kk;
        float w = WeL[(size_t)k*1024 + j];
        a0 += ete[k]        * w;
        a1 += ete[1024 + k] * w;
        a2 += ete[2048 + k] * w;
    }
    atomicAdd(&M3[j],        a0);
    atomicAdd(&M3[1024 + j], a1);
    atomicAdd(&M3[2048 + j], a2);
}

// ---------------------------------------------------------------- CSR build
__global__ void hist_k(const int* __restrict__ dsts, int* __restrict__ deg)
{ int e = blockIdx.x*256 + threadIdx.x; if (e < EE) atomicAdd(&deg[dsts[e]], 1); }

// single-block scan over NN degrees -> rp[0..NN] and cursor copy
__global__ __launch_bounds__(1024)
void scan_csr(const int* __restrict__ deg, int* __restrict__ rp, int* __restrict__ cursor)
{
    __shared__ int tot[1024];
    int t = threadIdx.x;
    int base = t * 10;
    int v[10];
    int run = 0;
#pragma unroll
    for (int j = 0; j < 10; ++j) {
        int i = base + j;
        int d = (i < NN) ? deg[i] : 0;
        run += d;
        v[j] = run;
    }
    tot[t] = run;
    __syncthreads();
    for (int d = 1; d < 1024; d <<= 1) {
        int xv = (t >= d) ? tot[t - d] : 0;
        __syncthreads();
        tot[t] += xv;
        __syncthreads();
    }
    int ex = (t == 0) ? 0 : tot[t - 1];
#pragma unroll
    for (int j = 0; j < 10; ++j) {
        int i = base + j;
        if (i < NN) {
            int incl = ex + v[j];
            rp[i + 1] = incl;
            if (i + 1 < NN) cursor[i + 1] = incl;
        }
    }
    if (t == 0) { rp[0] = 0; cursor[0] = 0; }
}

__global__ void fill_csr(const int* __restrict__ srcs, const int* __restrict__ dsts,
                         const int* __restrict__ etype, int* __restrict__ cursor,
                         int* __restrict__ sorted_src, int* __restrict__ sorted_typ)
{
    int e = blockIdx.x*256 + threadIdx.x;
    if (e < EE) {
        int d = dsts[e];
        int pos = atomicAdd(&cursor[d], 1);
        sorted_src[pos] = srcs[e];
        sorted_typ[pos] = etype[e];
    }
}

// ---------------------------------------------------------------- GEMM: BK=64 + XOR-swizzled LDS
template <typename OT>
__global__ __launch_bounds__(256)
void gemm_bt(const bf16_t* __restrict__ A, const bf16_t* __restrict__ BT,
             const float* __restrict__ bias, OT* __restrict__ Cmat,
             int K, int Ntot, int storeM, int mtiles, int ntiles)
{
    __shared__ __align__(16) bf16_t As[128*64];
    __shared__ __align__(16) bf16_t Bs[128*64];
    const int tid  = threadIdx.x;
    const int wave = tid >> 6;
    const int lane = tid & 63;

    const int GROUP_M = 8;
    int pid = blockIdx.x;
    int in_group = GROUP_M * ntiles;
    int gid = pid / in_group;
    int first_m = gid * GROUP_M;
    int gsz = mtiles - first_m; if (gsz > GROUP_M) gsz = GROUP_M;
    int local = pid % in_group;
    const int m0 = (first_m + (local % gsz)) * 128;
    const int n0 = (local / gsz) * 128;

    const int wm = (wave & 1) * 64;
    const int wn = (wave >> 1) * 64;
    const int quad = lane >> 4;
    const int l16  = lane & 15;

    const int srow = lane >> 3;
    const int gcol = ((lane & 7) ^ srow) * 8;

    f32x4 acc[4][4];
    f32x4 zero = {0.f, 0.f, 0.f, 0.f};
#pragma unroll
    for (int i = 0; i < 4; ++i)
#pragma unroll
        for (int j = 0; j < 4; ++j) acc[i][j] = zero;

    const bf16_t* aBase = A  + (size_t)(m0 + wave*8 + srow) * K + gcol;
    const bf16_t* bBase = BT + (size_t)(n0 + wave*8 + srow) * K + gcol;
    bf16_t* asDst = As + wave*512;
    bf16_t* bsDst = Bs + wave*512;

    for (int k0 = 0; k0 < K; k0 += 64) {
#pragma unroll
        for (int j = 0; j < 4; ++j)
            GLOAD_LDS16(aBase + (size_t)(j*32)*K + k0, asDst + j*2048);
#pragma unroll
        for (int j = 0; j < 4; ++j)
            GLOAD_LDS16(bBase + (size_t)(j*32)*K + k0, bsDst + j*2048);
        __syncthreads();
#pragma unroll
        for (int kk = 0; kk < 2; ++kk) {
            bf16x8 af[4], bfr[4];
#pragma unroll
            for (int mi = 0; mi < 4; ++mi) {
                int row = wm + mi*16 + l16;
                int ch  = ((kk*4 + quad) ^ (row & 7)) * 8;
                af[mi] = *(const bf16x8*)(As + row*64 + ch);
            }
#pragma unroll
            for (int ni = 0; ni < 4; ++ni) {
                int row = wn + ni*16 + l16;
                int ch  = ((kk*4 + quad) ^ (row & 7)) * 8;
                bfr[ni] = *(const bf16x8*)(Bs + row*64 + ch);
            }
#pragma unroll
            for (int mi = 0; mi < 4; ++mi)
#pragma unroll
                for (int ni = 0; ni < 4; ++ni)
                    acc[mi][ni] = __builtin_amdgcn_mfma_f32_16x16x32_bf16(af[mi], bfr[ni], acc[mi][ni], 0, 0, 0);
        }
        __syncthreads();
    }

#pragma unroll
    for (int mi = 0; mi < 4; ++mi) {
#pragma unroll
        for (int ni = 0; ni < 4; ++ni) {
            int col = n0 + wn + ni*16 + l16;
            float bv = bias[col];
#pragma unroll
            for (int r = 0; r < 4; ++r) {
                int row = m0 + wm + mi*16 + quad*4 + r;
                if (row < storeM)
                    Cmat[(size_t)row * Ntot + col] = (OT)(acc[mi][ni][r] + bv);
            }
        }
    }
}

// ---------------------------------------------------------------- fused edge kernel, two-phase
// phase 1: wave-per-edge logits (lane -> 16 ch, 3-shfl head reduce) -> s_p
// phase 2: serial-but-pipelined weighted aggregation (thread -> 4 ch)
__global__ __launch_bounds__(256)
void fused_edge(const int* __restrict__ rp, const int* __restrict__ ssrc,
                const int* __restrict__ styp, const bf16_t* __restrict__ XLXR,
                const float* __restrict__ M3, const float* __restrict__ attv,
                const float* __restrict__ cbias, bf16_t* __restrict__ hbuf)
{
    __shared__ float s_m3[3072];
    __shared__ float s_p[256*8];
    __shared__ int s_src[256];
    __shared__ int s_typ[256];
    __shared__ int s_cnt[3];

    int node = blockIdx.x;
    int tid = threadIdx.x;
    int lane = tid & 63;
    int wave = tid >> 6;

    for (int i = tid; i < 3072; i += 256) s_m3[i] = M3[i];
    if (tid < 3) s_cnt[tid] = 0;

    int b = rp[node], en = rp[node + 1];

    // phase-1 constants: lane -> 16 channels
    int c16 = lane * 16;
    bf16x8 xra = *(const bf16x8*)(XLXR + (size_t)node*2048 + 1024 + c16);
    bf16x8 xrb = *(const bf16x8*)(XLXR + (size_t)node*2048 + 1024 + c16 + 8);
    float xr16[16], at16[16];
#pragma unroll
    for (int j = 0; j < 8; ++j) { xr16[j] = (float)xra[j]; xr16[8+j] = (float)xrb[j]; }
#pragma unroll
    for (int j = 0; j < 16; ++j) at16[j] = attv[c16 + j];

    // phase-2 / self-loop constants: thread -> 4 channels
    int c = tid * 4;
    int head = tid >> 5;
    bf16x4 xlv = *(const bf16x4*)(XLXR + (size_t)node*2048 + c);
    bf16x4 xrv = *(const bf16x4*)(XLXR + (size_t)node*2048 + 1024 + c);
    float at0 = attv[c], at1 = attv[c+1], at2 = attv[c+2], at3 = attv[c+3];

    float a0 = 0.f, a1 = 0.f, a2 = 0.f, a3 = 0.f;
    float den = 0.f;

    for (int base = b; base < en; base += 256) {
        int nchunk = en - base; if (nchunk > 256) nchunk = 256;
        __syncthreads();
        if (tid < nchunk) { s_src[tid] = ssrc[base + tid]; s_typ[tid] = styp[base + tid]; }
        __syncthreads();
        // ---- phase 1: logits, 4 edges in flight (one per wave)
        for (int i = wave; i < nchunk; i += 4) {
            int s = s_src[i];
            int t = s_typ[i];
            bf16x8 xa = *(const bf16x8*)(XLXR + (size_t)s*2048 + c16);
            bf16x8 xb = *(const bf16x8*)(XLXR + (size_t)s*2048 + c16 + 8);
            const float* m3p = s_m3 + t*1024 + c16;
            float part = 0.f;
#pragma unroll
            for (int j = 0; j < 8; ++j) {
                float v = (float)xa[j] + xr16[j] + m3p[j];
                v = (v > 0.f) ? v : NEGS * v;
                part += v * at16[j];
            }
#pragma unroll
            for (int j = 0; j < 8; ++j) {
                float v = (float)xb[j] + xr16[8+j] + m3p[8+j];
                v = (v > 0.f) ? v : NEGS * v;
                part += v * at16[8+j];
            }
            part += __shfl_xor(part, 1);
            part += __shfl_xor(part, 2);
            part += __shfl_xor(part, 4);   // 8-lane head group complete
            if ((lane & 7) == 0) {
                part = fminf(fmaxf(part, -60.f), 60.f);
                s_p[i*8 + (lane >> 3)] = __expf(part);
            }
            if (lane == 0) atomicAdd(&s_cnt[t], 1);
        }
        __syncthreads();
        // ---- phase 2: weighted aggregation (rows now L2-hot)
#pragma unroll 2
        for (int i = 0; i < nchunk; ++i) {
            float p = s_p[i*8 + head];
            bf16x4 xs = *(const bf16x4*)(XLXR + (size_t)s_src[i]*2048 + c);
            den += p;
            a0 += p*(float)xs[0]; a1 += p*(float)xs[1];
            a2 += p*(float)xs[2]; a3 += p*(float)xs[3];
        }
    }
    __syncthreads();   // covers zero-degree nodes (s_cnt init visibility)

    // ---- self loop
    float cnt0 = (float)s_cnt[0], cnt1 = (float)s_cnt[1], cnt2 = (float)s_cnt[2];
    float degf = cnt0 + cnt1 + cnt2;
    float inv = 1.f / fmaxf(degf, 1.f);
    float w0 = cnt0 * inv, w1 = cnt1 * inv, w2 = cnt2 * inv;
    float sx0 = (float)xlv[0], sx1 = (float)xlv[1], sx2 = (float)xlv[2], sx3 = (float)xlv[3];
    float xr0 = (float)xrv[0], xr1 = (float)xrv[1], xr2 = (float)xrv[2], xr3 = (float)xrv[3];
    float e0 = w0*s_m3[c+0] + w1*s_m3[1024+c+0] + w2*s_m3[2048+c+0];
    float e1 = w0*s_m3[c+1] + w1*s_m3[1024+c+1] + w2*s_m3[2048+c+1];
    float e2 = w0*s_m3[c+2] + w1*s_m3[1024+c+2] + w2*s_m3[2048+c+2];
    float e3 = w0*s_m3[c+3] + w1*s_m3[1024+c+3] + w2*s_m3[2048+c+3];
    float u0 = sx0 + xr0 + e0; u0 = (u0 > 0.f) ? u0 : NEGS * u0;
    float u1 = sx1 + xr1 + e1; u1 = (u1 > 0.f) ? u1 : NEGS * u1;
    float u2 = sx2 + xr2 + e2; u2 = (u2 > 0.f) ? u2 : NEGS * u2;
    float u3 = sx3 + xr3 + e3; u3 = (u3 > 0.f) ? u3 : NEGS * u3;
    float sp = u0*at0 + u1*at1 + u2*at2 + u3*at3;
    sp += __shfl_xor(sp, 1);
    sp += __shfl_xor(sp, 2);
    sp += __shfl_xor(sp, 4);
    sp += __shfl_xor(sp, 8);
    sp += __shfl_xor(sp, 16);
    sp = fminf(fmaxf(sp, -60.f), 60.f);
    float ps = __expf(sp);
    den += ps;
    a0 += ps * sx0; a1 += ps * sx1; a2 += ps * sx2; a3 += ps * sx3;

    float invd = 1.f / den;
    bf16x4 hv = *(const bf16x4*)(hbuf + (size_t)node*1024 + c);
    const float* cb = cbias + c;
    bf16x4 outv;
    outv[0] = (bf16_t)((float)hv[0] + fmaxf(a0*invd + cb[0], 0.f));
    outv[1] = (bf16_t)((float)hv[1] + fmaxf(a1*invd + cb[1], 0.f));
    outv[2] = (bf16_t)((float)hv[2] + fmaxf(a2*invd + cb[2], 0.f));
    outv[3] = (bf16_t)((float)hv[3] + fmaxf(a3*invd + cb[3], 0.f));
    *(bf16x4*)(hbuf + (size_t)node*1024 + c) = outv;
}

// ---------------------------------------------------------------- launch
extern "C" void kernel_launch(void* const* d_in, const int* in_sizes, int n_in,
                              void* d_out, int out_size, void* d_ws, size_t ws_size,
                              hipStream_t stream)
{
    (void)in_sizes; (void)n_in; (void)out_size; (void)ws_size;
    const float* x     = (const float*)d_in[0];
    const int*   eidx  = (const int*)d_in[1];
    const int*   etype = (const int*)d_in[2];
    const int*   ntyp  = (const int*)d_in[3];
    const float* nte   = (const float*)d_in[4];
    const float* ete   = (const float*)d_in[5];
    const float* Wl    = (const float*)d_in[6];
    const float* bl    = (const float*)d_in[7];
    const float* Wr    = (const float*)d_in[8];
    const float* br    = (const float*)d_in[9];
    const float* We    = (const float*)d_in[10];
    const float* attw  = (const float*)d_in[11];
    const float* cbias = (const float*)d_in[12];
    const float* outW  = (const float*)d_in[13];
    const float* outb  = (const float*)d_in[14];
    const int* srcs = eidx;
    const int* dsts = eidx + EE;

    char* wsp = (char*)d_ws;
    size_t off = 0;
    auto carve = [&](size_t bytes) -> void* {
        void* pp = wsp + off;
        off += (bytes + 255) & ~(size_t)255;
        return pp;
    };
    bf16_t* hbuf  = (bf16_t*)carve((size_t)MPAD*1024*2);
    bf16_t* XLXR  = (bf16_t*)carve((size_t)MPAD*2048*2);
    bf16_t* WT    = (bf16_t*)carve((size_t)LL*2048*1024*2);
    bf16_t* OWT   = (bf16_t*)carve((size_t)1024*1024*2);
    float*  M3L   = (float*)carve((size_t)LL*3072*4);
    float*  biasb = (float*)carve(5120*4);
    int* deg    = (int*)carve((size_t)NN*4);
    int* rp     = (int*)carve((size_t)(NN+1)*4);
    int* cursor = (int*)carve((size_t)NN*4);
    int* ssrc   = (int*)carve((size_t)EE*4);
    int* styp   = (int*)carve((size_t)EE*4);

    preamble<<<10260, 256, 0, stream>>>(Wl, Wr, outW, WT, OWT,
                                        x, ntyp, nte, hbuf,
                                        bl, br, outb, biasb, M3L, deg);
    compute_m3_all<<<512, 256, 0, stream>>>(ete, We, M3L);
    hist_k<<<(EE + 255)/256, 256, 0, stream>>>(dsts, deg);
    scan_csr<<<1, 1024, 0, stream>>>(deg, rp, cursor);
    fill_csr<<<(EE + 255)/256, 256, 0, stream>>>(srcs, dsts, etype, cursor, ssrc, styp);

    for (int l = 0; l < LL; ++l) {
        gemm_bt<bf16_t><<<79*16, 256, 0, stream>>>(hbuf, WT + (size_t)l*2048*1024,
                                                   biasb + l*2048, XLXR,
                                                   1024, 2048, MPAD, 79, 16);
        fused_edge<<<NN, 256, 0, stream>>>(rp, ssrc, styp, XLXR, M3L + l*3072, attw + l*1024,
                                           cbias + l*1024, hbuf);
    }

    gemm_bt<float><<<79*8, 256, 0, stream>>>(hbuf, OWT, biasb + 4096, (float*)d_out,
                                             1024, 1024, NN, 79, 8);
}

// Round 7
// 403.974 us; speedup vs baseline: 1.1775x; 1.1775x over previous
//
#include <hip/hip_runtime.h>
#include <hip/hip_bf16.h>
#include <stdint.h>

typedef __bf16 bf16_t;
typedef bf16_t bf16x8 __attribute__((ext_vector_type(8)));
typedef bf16_t bf16x4 __attribute__((ext_vector_type(4)));
typedef float f32x4 __attribute__((ext_vector_type(4)));

#define NN 10000
#define EE 80000
#define DD 1024
#define LL 2
#define MPAD 10112   /* 79*128 */
#define NEGS 0.2f

#define GLOAD_LDS16(g, l) \
    __builtin_amdgcn_global_load_lds((__attribute__((address_space(1))) void*)(void*)(g), \
                                     (__attribute__((address_space(3))) void*)(l), 16, 0, 0)

// ---------------------------------------------------------------- mega-preamble
__global__ __launch_bounds__(256)
void preamble(const float* __restrict__ Wl, const float* __restrict__ Wr,
              const float* __restrict__ outW, bf16_t* __restrict__ WT,
              bf16_t* __restrict__ OWT,
              const float* __restrict__ x, const int* __restrict__ ntypes,
              const float* __restrict__ nte, bf16_t* __restrict__ hbuf,
              const float* __restrict__ bl, const float* __restrict__ br,
              const float* __restrict__ outb, float* __restrict__ biasb,
              float* __restrict__ M3L, int* __restrict__ deg)
{
    __shared__ float tile[32][33];
    int b = blockIdx.x;
    int tid = threadIdx.x;
    if (b < 5120) {
        int z = b >> 10, rem = b & 1023;
        int bx = rem & 31, by = rem >> 5;
        const float* src;
        bf16_t* dstp;
        switch (z) {
            case 0: src = Wl;                       dstp = WT;                        break;
            case 1: src = Wr;                       dstp = WT + (size_t)1024*1024;    break;
            case 2: src = Wl + (size_t)1024*1024;   dstp = WT + (size_t)2*1024*1024;  break;
            case 3: src = Wr + (size_t)1024*1024;   dstp = WT + (size_t)3*1024*1024;  break;
            default: src = outW;                    dstp = OWT;                       break;
        }
        int tx = tid & 31, ty = tid >> 5;
#pragma unroll
        for (int i = 0; i < 4; ++i)
            tile[ty + i*8][tx] = src[(size_t)(by*32 + ty + i*8)*1024 + bx*32 + tx];
        __syncthreads();
#pragma unroll
        for (int i = 0; i < 4; ++i)
            dstp[(size_t)(bx*32 + ty + i*8)*1024 + by*32 + tx] = (bf16_t)tile[tx][ty + i*8];
    } else if (b < 10176) {
        size_t idx = ((size_t)(b - 5120)*256 + tid) * 8;
        if (idx >= (size_t)MPAD*1024) return;
        int n = (int)(idx >> 10);
        int c = (int)(idx & 1023);
        bf16x8 outv;
        if (n < NN) {
            const float* xp = x + (size_t)n*1024 + c;
            int t = ntypes[n];
            const float* ep = nte + (size_t)t*1024 + c;
#pragma unroll
            for (int j = 0; j < 8; ++j) outv[j] = (bf16_t)(xp[j] + ep[j]);
        } else {
#pragma unroll
            for (int j = 0; j < 8; ++j) outv[j] = (bf16_t)0.f;
        }
        *(bf16x8*)(hbuf + idx) = outv;
    } else if (b < 10196) {
        int i = (b - 10176)*256 + tid;
        if (i < 4096) {
            int l = i >> 11, j = i & 2047;
            biasb[i] = (j < 1024) ? bl[l*1024 + j] : br[l*1024 + j - 1024];
        } else if (i < 5120) {
            biasb[i] = outb[i - 4096];
        }
    } else if (b < 10220) {
        int i = (b - 10196)*256 + tid;
        if (i < LL*3072) M3L[i] = 0.f;
    } else {
        int i = (b - 10220)*256 + tid;
        if (i < NN) deg[i] = 0;
    }
}

// ---------------------------------------------------------------- M3 (both layers, one launch)
__global__ __launch_bounds__(256)
void compute_m3_all(const float* __restrict__ ete, const float* __restrict__ We,
                    float* __restrict__ M3L)
{
    int l   = blockIdx.x >> 8;
    int bid = blockIdx.x & 255;
    const float* WeL = We + (size_t)l*1024*1024;
    float* M3 = M3L + l*3072;
    int j  = (bid & 3) * 256 + threadIdx.x;
    int k0 = (bid >> 2) * 16;
    float a0 = 0.f, a1 = 0.f, a2 = 0.f;
#pragma unroll
    for (int kk = 0; kk < 16; ++kk) {
        int k = k0 + kk;
        float w = WeL[(size_t)k*1024 + j];
        a0 += ete[k]        * w;
        a1 += ete[1024 + k] * w;
        a2 += ete[2048 + k] * w;
    }
    atomicAdd(&M3[j],        a0);
    atomicAdd(&M3[1024 + j], a1);
    atomicAdd(&M3[2048 + j], a2);
}

// ---------------------------------------------------------------- CSR build
__global__ void hist_k(const int* __restrict__ dsts, int* __restrict__ deg)
{ int e = blockIdx.x*256 + threadIdx.x; if (e < EE) atomicAdd(&deg[dsts[e]], 1); }

__global__ __launch_bounds__(1024)
void scan_csr(const int* __restrict__ deg, int* __restrict__ rp, int* __restrict__ cursor)
{
    __shared__ int tot[1024];
    int t = threadIdx.x;
    int base = t * 10;
    int v[10];
    int run = 0;
#pragma unroll
    for (int j = 0; j < 10; ++j) {
        int i = base + j;
        int d = (i < NN) ? deg[i] : 0;
        run += d;
        v[j] = run;
    }
    tot[t] = run;
    __syncthreads();
    for (int d = 1; d < 1024; d <<= 1) {
        int xv = (t >= d) ? tot[t - d] : 0;
        __syncthreads();
        tot[t] += xv;
        __syncthreads();
    }
    int ex = (t == 0) ? 0 : tot[t - 1];
#pragma unroll
    for (int j = 0; j < 10; ++j) {
        int i = base + j;
        if (i < NN) {
            int incl = ex + v[j];
            rp[i + 1] = incl;
            if (i + 1 < NN) cursor[i + 1] = incl;
        }
    }
    if (t == 0) { rp[0] = 0; cursor[0] = 0; }
}

__global__ void fill_csr(const int* __restrict__ srcs, const int* __restrict__ dsts,
                         const int* __restrict__ etype, int* __restrict__ cursor,
                         int* __restrict__ sorted_src, int* __restrict__ sorted_typ)
{
    int e = blockIdx.x*256 + threadIdx.x;
    if (e < EE) {
        int d = dsts[e];
        int pos = atomicAdd(&cursor[d], 1);
        sorted_src[pos] = srcs[e];
        sorted_typ[pos] = etype[e];
    }
}

// ---------------------------------------------------------------- GEMM: BK=64 + XOR-swizzled LDS
template <typename OT>
__global__ __launch_bounds__(256)
void gemm_bt(const bf16_t* __restrict__ A, const bf16_t* __restrict__ BT,
             const float* __restrict__ bias, OT* __restrict__ Cmat,
             int K, int Ntot, int storeM, int mtiles, int ntiles)
{
    __shared__ __align__(16) bf16_t As[128*64];
    __shared__ __align__(16) bf16_t Bs[128*64];
    const int tid  = threadIdx.x;
    const int wave = tid >> 6;
    const int lane = tid & 63;

    const int GROUP_M = 8;
    int pid = blockIdx.x;
    int in_group = GROUP_M * ntiles;
    int gid = pid / in_group;
    int first_m = gid * GROUP_M;
    int gsz = mtiles - first_m; if (gsz > GROUP_M) gsz = GROUP_M;
    int local = pid % in_group;
    const int m0 = (first_m + (local % gsz)) * 128;
    const int n0 = (local / gsz) * 128;

    const int wm = (wave & 1) * 64;
    const int wn = (wave >> 1) * 64;
    const int quad = lane >> 4;
    const int l16  = lane & 15;

    const int srow = lane >> 3;
    const int gcol = ((lane & 7) ^ srow) * 8;

    f32x4 acc[4][4];
    f32x4 zero = {0.f, 0.f, 0.f, 0.f};
#pragma unroll
    for (int i = 0; i < 4; ++i)
#pragma unroll
        for (int j = 0; j < 4; ++j) acc[i][j] = zero;

    const bf16_t* aBase = A  + (size_t)(m0 + wave*8 + srow) * K + gcol;
    const bf16_t* bBase = BT + (size_t)(n0 + wave*8 + srow) * K + gcol;
    bf16_t* asDst = As + wave*512;
    bf16_t* bsDst = Bs + wave*512;

    for (int k0 = 0; k0 < K; k0 += 64) {
#pragma unroll
        for (int j = 0; j < 4; ++j)
            GLOAD_LDS16(aBase + (size_t)(j*32)*K + k0, asDst + j*2048);
#pragma unroll
        for (int j = 0; j < 4; ++j)
            GLOAD_LDS16(bBase + (size_t)(j*32)*K + k0, bsDst + j*2048);
        __syncthreads();
#pragma unroll
        for (int kk = 0; kk < 2; ++kk) {
            bf16x8 af[4], bfr[4];
#pragma unroll
            for (int mi = 0; mi < 4; ++mi) {
                int row = wm + mi*16 + l16;
                int ch  = ((kk*4 + quad) ^ (row & 7)) * 8;
                af[mi] = *(const bf16x8*)(As + row*64 + ch);
            }
#pragma unroll
            for (int ni = 0; ni < 4; ++ni) {
                int row = wn + ni*16 + l16;
                int ch  = ((kk*4 + quad) ^ (row & 7)) * 8;
                bfr[ni] = *(const bf16x8*)(Bs + row*64 + ch);
            }
#pragma unroll
            for (int mi = 0; mi < 4; ++mi)
#pragma unroll
                for (int ni = 0; ni < 4; ++ni)
                    acc[mi][ni] = __builtin_amdgcn_mfma_f32_16x16x32_bf16(af[mi], bfr[ni], acc[mi][ni], 0, 0, 0);
        }
        __syncthreads();
    }

#pragma unroll
    for (int mi = 0; mi < 4; ++mi) {
#pragma unroll
        for (int ni = 0; ni < 4; ++ni) {
            int col = n0 + wn + ni*16 + l16;
            float bv = bias[col];
#pragma unroll
            for (int r = 0; r < 4; ++r) {
                int row = m0 + wm + mi*16 + quad*4 + r;
                if (row < storeM)
                    Cmat[(size_t)row * Ntot + col] = (OT)(acc[mi][ni][r] + bv);
            }
        }
    }
}

// ---------------------------------------------------------------- fused: logits + softmax + aggregate + residual
// (round-5 proven structure: single pass, row read ONCE per edge)
__global__ __launch_bounds__(256)
void fused_edge(const int* __restrict__ rp, const int* __restrict__ ssrc,
                const int* __restrict__ styp, const bf16_t* __restrict__ XLXR,
                const float* __restrict__ M3, const float* __restrict__ attv,
                const float* __restrict__ cbias, bf16_t* __restrict__ hbuf)
{
    int node = blockIdx.x;
    int tid = threadIdx.x;
    int c = tid * 4;
    __shared__ int s_src[256];
    __shared__ int s_typ[256];

    int b = rp[node], en = rp[node + 1];

    bf16x4 xlv = *(const bf16x4*)(XLXR + (size_t)node*2048 + c);
    bf16x4 xrv = *(const bf16x4*)(XLXR + (size_t)node*2048 + 1024 + c);
    float xr0 = (float)xrv[0], xr1 = (float)xrv[1], xr2 = (float)xrv[2], xr3 = (float)xrv[3];
    float at0 = attv[c], at1 = attv[c+1], at2 = attv[c+2], at3 = attv[c+3];
    float m3r[3][4];
#pragma unroll
    for (int t = 0; t < 3; ++t)
#pragma unroll
        for (int j = 0; j < 4; ++j) m3r[t][j] = M3[t*1024 + c + j];

    float a0 = 0.f, a1 = 0.f, a2 = 0.f, a3 = 0.f;
    float den = 0.f;
    float cnt0 = 0.f, cnt1 = 0.f, cnt2 = 0.f;

    for (int base = b; base < en; base += 256) {
        int nchunk = en - base; if (nchunk > 256) nchunk = 256;
        __syncthreads();
        if (tid < nchunk) { s_src[tid] = ssrc[base + tid]; s_typ[tid] = styp[base + tid]; }
        __syncthreads();
#pragma unroll 2
        for (int i = 0; i < nchunk; ++i) {
            int s = s_src[i];
            int t = s_typ[i];
            bf16x4 xs = *(const bf16x4*)(XLXR + (size_t)s*2048 + c);
            float x0 = (float)xs[0], x1 = (float)xs[1], x2 = (float)xs[2], x3 = (float)xs[3];
            float v0 = x0 + xr0 + m3r[t][0]; v0 = (v0 > 0.f) ? v0 : NEGS * v0;
            float v1 = x1 + xr1 + m3r[t][1]; v1 = (v1 > 0.f) ? v1 : NEGS * v1;
            float v2 = x2 + xr2 + m3r[t][2]; v2 = (v2 > 0.f) ? v2 : NEGS * v2;
            float v3 = x3 + xr3 + m3r[t][3]; v3 = (v3 > 0.f) ? v3 : NEGS * v3;
            float part = v0*at0 + v1*at1 + v2*at2 + v3*at3;
            part += __shfl_xor(part, 1);
            part += __shfl_xor(part, 2);
            part += __shfl_xor(part, 4);
            part += __shfl_xor(part, 8);
            part += __shfl_xor(part, 16);
            part = fminf(fmaxf(part, -60.f), 60.f);
            float p = __expf(part);
            cnt0 += (t == 0) ? 1.f : 0.f;
            cnt1 += (t == 1) ? 1.f : 0.f;
            cnt2 += (t == 2) ? 1.f : 0.f;
            den += p;
            a0 += p * x0; a1 += p * x1; a2 += p * x2; a3 += p * x3;
        }
    }

    float deg = cnt0 + cnt1 + cnt2;
    float inv = 1.f / fmaxf(deg, 1.f);
    float w0 = cnt0 * inv, w1 = cnt1 * inv, w2 = cnt2 * inv;
    float sx0 = (float)xlv[0], sx1 = (float)xlv[1], sx2 = (float)xlv[2], sx3 = (float)xlv[3];
    float e0 = w0*m3r[0][0] + w1*m3r[1][0] + w2*m3r[2][0];
    float e1 = w0*m3r[0][1] + w1*m3r[1][1] + w2*m3r[2][1];
    float e2 = w0*m3r[0][2] + w1*m3r[1][2] + w2*m3r[2][2];
    float e3 = w0*m3r[0][3] + w1*m3r[1][3] + w2*m3r[2][3];
    float u0 = sx0 + xr0 + e0; u0 = (u0 > 0.f) ? u0 : NEGS * u0;
    float u1 = sx1 + xr1 + e1; u1 = (u1 > 0.f) ? u1 : NEGS * u1;
    float u2 = sx2 + xr2 + e2; u2 = (u2 > 0.f) ? u2 : NEGS * u2;
    float u3 = sx3 + xr3 + e3; u3 = (u3 > 0.f) ? u3 : NEGS * u3;
    float sp = u0*at0 + u1*at1 + u2*at2 + u3*at3;
    sp += __shfl_xor(sp, 1);
    sp += __shfl_xor(sp, 2);
    sp += __shfl_xor(sp, 4);
    sp += __shfl_xor(sp, 8);
    sp += __shfl_xor(sp, 16);
    sp = fminf(fmaxf(sp, -60.f), 60.f);
    float ps = __expf(sp);
    den += ps;
    a0 += ps * sx0; a1 += ps * sx1; a2 += ps * sx2; a3 += ps * sx3;

    float invd = 1.f / den;
    bf16x4 hv = *(const bf16x4*)(hbuf + (size_t)node*1024 + c);
    const float* cb = cbias + c;
    bf16x4 outv;
    outv[0] = (bf16_t)((float)hv[0] + fmaxf(a0*invd + cb[0], 0.f));
    outv[1] = (bf16_t)((float)hv[1] + fmaxf(a1*invd + cb[1], 0.f));
    outv[2] = (bf16_t)((float)hv[2] + fmaxf(a2*invd + cb[2], 0.f));
    outv[3] = (bf16_t)((float)hv[3] + fmaxf(a3*invd + cb[3], 0.f));
    *(bf16x4*)(hbuf + (size_t)node*1024 + c) = outv;
}

// ---------------------------------------------------------------- launch
extern "C" void kernel_launch(void* const* d_in, const int* in_sizes, int n_in,
                              void* d_out, int out_size, void* d_ws, size_t ws_size,
                              hipStream_t stream)
{
    (void)in_sizes; (void)n_in; (void)out_size; (void)ws_size;
    const float* x     = (const float*)d_in[0];
    const int*   eidx  = (const int*)d_in[1];
    const int*   etype = (const int*)d_in[2];
    const int*   ntyp  = (const int*)d_in[3];
    const float* nte   = (const float*)d_in[4];
    const float* ete   = (const float*)d_in[5];
    const float* Wl    = (const float*)d_in[6];
    const float* bl    = (const float*)d_in[7];
    const float* Wr    = (const float*)d_in[8];
    const float* br    = (const float*)d_in[9];
    const float* We    = (const float*)d_in[10];
    const float* attw  = (const float*)d_in[11];
    const float* cbias = (const float*)d_in[12];
    const float* outW  = (const float*)d_in[13];
    const float* outb  = (const float*)d_in[14];
    const int* srcs = eidx;
    const int* dsts = eidx + EE;

    char* wsp = (char*)d_ws;
    size_t off = 0;
    auto carve = [&](size_t bytes) -> void* {
        void* pp = wsp + off;
        off += (bytes + 255) & ~(size_t)255;
        return pp;
    };
    bf16_t* hbuf  = (bf16_t*)carve((size_t)MPAD*1024*2);
    bf16_t* XLXR  = (bf16_t*)carve((size_t)MPAD*2048*2);
    bf16_t* WT    = (bf16_t*)carve((size_t)LL*2048*1024*2);
    bf16_t* OWT   = (bf16_t*)carve((size_t)1024*1024*2);
    float*  M3L   = (float*)carve((size_t)LL*3072*4);
    float*  biasb = (float*)carve(5120*4);
    int* deg    = (int*)carve((size_t)NN*4);
    int* rp     = (int*)carve((size_t)(NN+1)*4);
    int* cursor = (int*)carve((size_t)NN*4);
    int* ssrc   = (int*)carve((size_t)EE*4);
    int* styp   = (int*)carve((size_t)EE*4);

    preamble<<<10260, 256, 0, stream>>>(Wl, Wr, outW, WT, OWT,
                                        x, ntyp, nte, hbuf,
                                        bl, br, outb, biasb, M3L, deg);
    compute_m3_all<<<512, 256, 0, stream>>>(ete, We, M3L);
    hist_k<<<(EE + 255)/256, 256, 0, stream>>>(dsts, deg);
    scan_csr<<<1, 1024, 0, stream>>>(deg, rp, cursor);
    fill_csr<<<(EE + 255)/256, 256, 0, stream>>>(srcs, dsts, etype, cursor, ssrc, styp);

    for (int l = 0; l < LL; ++l) {
        gemm_bt<bf16_t><<<79*16, 256, 0, stream>>>(hbuf, WT + (size_t)l*2048*1024,
                                                   biasb + l*2048, XLXR,
                                                   1024, 2048, MPAD, 79, 16);
        fused_edge<<<NN, 256, 0, stream>>>(rp, ssrc, styp, XLXR, M3L + l*3072, attw + l*1024,
                                           cbias + l*1024, hbuf);
    }

    gemm_bt<float><<<79*8, 256, 0, stream>>>(hbuf, OWT, biasb + 4096, (float*)d_out,
                                             1024, 1024, NN, 79, 8);
}